// Round 4
// baseline (189.829 us; speedup 1.0000x reference)
//
#include <hip/hip_runtime.h>
#include <hip/hip_bf16.h>

// NT-Xent loss, 2B=8192, D=128, T=0.5. TWO dispatches, NO device fences:
//  k_prep : row-normalize -> bf16 nb; picked logit per row (fp32); zero
//           l_arr and the completion counter.
//  k_gemm : SYMMETRIC Gram, upper-triangle 128x128 tiles via circulant
//           pairing bj=(bi+by)&63, by in [0,32]. Block (bi,g) handles TWO
//           strips {g, g+17}; A fragments loaded once; row sums carried in
//           registers across both strips.
//           v5: each strip split into two 64-col HALF tiles (16 KB); two
//           16 KB LDS buffers ping-pong over 4 phases with COUNTED vmcnt
//           waits (4/8/12/8 - atomics included in the counts, never
//           waited) + raw s_barrier. 32 KB LDS total -> 4 blocks/CU
//           (16 waves/CU, = R0) AND counted-vmcnt pipelining (v4 had the
//           pipeline but only 8 waves/CU -> net loss). Col sums via
//           quad-reduce + direct atomicAdd (verified absmax 0).
//           k_final FOLDED IN: last block (atomic counter + threadfence)
//           reduces 2 + ln(l_arr[i]) - picked[i] into out.
//           Fixed softmax max = 2.0 (cos<=1).

typedef __bf16 bf16x8 __attribute__((ext_vector_type(8)));
typedef float floatx4 __attribute__((ext_vector_type(4)));

#define TWO_B 8192
#define B_HALF 4096
#define D 128
#define INV_T 2.0f                 // 1/temperature
#define FIXED_MAX 2.0f             // logit upper bound (cos<=1)
#define C_EXP 2.885390081777927f   // INV_T * log2(e) == FIXED_MAX * log2(e)
#define NBLK (64 * 17)

#if defined(__has_builtin) && __has_builtin(__builtin_amdgcn_exp2f)
#define EXP2F(x) __builtin_amdgcn_exp2f(x)   // raw v_exp_f32; arg in [-5.8, 0]
#else
#define EXP2F(x) exp2f(x)
#endif
#if defined(__has_builtin) && __has_builtin(__builtin_amdgcn_logf)
#define LOG2F(x) __builtin_amdgcn_logf(x)    // raw v_log_f32 (log2)
#else
#define LOG2F(x) log2f(x)
#endif

__device__ inline void load16_lds(const __bf16* g, __bf16* l) {
    __builtin_amdgcn_global_load_lds(
        (const __attribute__((address_space(1))) unsigned int*)g,
        (__attribute__((address_space(3))) unsigned int*)l, 16, 0, 0);
}

// -------- kernel 1: normalize + picked + zero l_arr & counter ------------
__global__ void k_prep(const float* __restrict__ emb,
                       const int* __restrict__ labels,
                       __bf16* __restrict__ nb,
                       float* __restrict__ picked,
                       float* __restrict__ l_arr,
                       unsigned int* __restrict__ cnt) {
    int wv   = threadIdx.x >> 6;
    int lane = threadIdx.x & 63;
    int i = blockIdx.x * 4 + wv;
    const float2* e2 = reinterpret_cast<const float2*>(emb + (size_t)i * D);
    float2 v = e2[lane];
    float ssi = v.x * v.x + v.y * v.y;
    // picked column: labels[i] skips cols {i, i^4096}
    int p = i ^ B_HALF;
    int a = min(i, p), b = max(i, p);
    int l = labels[i];
    int c = l + (l >= a);
    c += (c >= b);
    const float2* ec2 = reinterpret_cast<const float2*>(emb + (size_t)c * D);
    float2 u = ec2[lane];
    float dot = v.x * u.x + v.y * u.y;
    float ssc = u.x * u.x + u.y * u.y;
#pragma unroll
    for (int off = 32; off >= 1; off >>= 1) {
        ssi += __shfl_xor(ssi, off, 64);
        dot += __shfl_xor(dot, off, 64);
        ssc += __shfl_xor(ssc, off, 64);
    }
    float rn = rsqrtf(fmaxf(ssi, 1e-16f));
    union { __bf16 h[2]; unsigned int uu; } pk;
    pk.h[0] = (__bf16)(v.x * rn);
    pk.h[1] = (__bf16)(v.y * rn);
    reinterpret_cast<unsigned int*>(nb)[i * 64 + lane] = pk.uu;
    if (lane == 0)
        picked[i] = dot / fmaxf(sqrtf(ssi * ssc), 1e-8f) * INV_T;
    if (blockIdx.x < TWO_B / 256) l_arr[blockIdx.x * 256 + threadIdx.x] = 0.f;
    if (blockIdx.x == 0 && threadIdx.x == 0) *cnt = 0u;
}

// -------- kernel 2: symmetric Gram MFMA + masked exp-sum + final ---------
// grid (64, 17), block 256 = 4 waves.
__global__ __launch_bounds__(256, 4) void k_gemm(const __bf16* __restrict__ nb,
                                                 float* __restrict__ l_arr,
                                                 const float* __restrict__ picked,
                                                 float* __restrict__ out,
                                                 unsigned int* __restrict__ cnt) {
    __shared__ __bf16 lds[2][8192];          // 2 x 16 KB half-tile buffers
    __shared__ unsigned int last_flag;
    __shared__ float fred[4];

    const int bi = blockIdx.x;
    const int g  = blockIdx.y;

    const int lane = threadIdx.x & 63;
    const int w    = threadIdx.x >> 6;
    const int m    = lane & 15;
    const int quad = lane >> 4;
    const int row0 = bi * 128 + w * 32;      // wave rows: row0..row0+31

    // A fragments: two 16-row tiles, full K=128, loaded + pinned FIRST so
    // the pin's implicit waitcnt drains only the A loads (stage counts
    // below are then exact).
    bf16x8 a0[4], a1[4];
#pragma unroll
    for (int kc = 0; kc < 4; ++kc) {
        a0[kc] = *reinterpret_cast<const bf16x8*>(
            nb + (size_t)(row0 + m) * D + kc * 32 + quad * 8);
        a1[kc] = *reinterpret_cast<const bf16x8*>(
            nb + (size_t)(row0 + 16 + m) * D + kc * 32 + quad * 8);
    }
    asm volatile("" : "+v"(a0[0]), "+v"(a0[1]), "+v"(a0[2]), "+v"(a0[3]),
                      "+v"(a1[0]), "+v"(a1[1]), "+v"(a1[2]), "+v"(a1[3]));

    float l0[4] = {0.f, 0.f, 0.f, 0.f};      // row sums, carried across strips
    float l1[4] = {0.f, 0.f, 0.f, 0.f};
    const int i0 = row0 + quad * 4;          // l0 rows; l1 rows = i0+16

    const int  bj0   = (bi + g) & 63;
    const bool diag0 = (g == 0);
    const bool has1  = (g < 15) || (g == 15 && bi < 32);
    const int  bj1   = (bi + g + 17) & 63;
    const bool bmask1 = (g == 15);           // by==32 partner-pair masking

    __bf16* buf0 = &lds[0][0];
    __bf16* buf1 = &lds[1][0];

    // stage one 64-col x 128-K half tile (16 KB): 4 gl_lds per wave.
    // LDS elem j*2048 + w*512 + lane*8+e <-> nb[(c0h+16j+m)*D + w*32+quad*8+e]
    auto stage_half = [&](int bj, int h, __bf16* buf) {
        const __bf16* gp = nb + (size_t)(bj * 128 + h * 64 + m) * D + w * 32 + quad * 8;
#pragma unroll
        for (int j = 0; j < 4; ++j)
            load16_lds(gp + (size_t)j * 16 * D, &buf[j * 2048 + w * 512]);
    };

    auto mfma_half = [&](const __bf16* buf, floatx4 (&A0)[4], floatx4 (&A1)[4]) {
#pragma unroll
        for (int j = 0; j < 4; ++j) { A0[j] = {0.f,0.f,0.f,0.f}; A1[j] = {0.f,0.f,0.f,0.f}; }
#pragma unroll
        for (int kc = 0; kc < 4; ++kc) {
            const bf16x8 a0k = a0[kc], a1k = a1[kc];
#pragma unroll
            for (int j = 0; j < 4; ++j) {
                bf16x8 b = *reinterpret_cast<const bf16x8*>(
                    &buf[(j * 4 + kc) * 512 + lane * 8]);
                A0[j] = __builtin_amdgcn_mfma_f32_16x16x32_bf16(a0k, b, A0[j], 0, 0, 0);
                A1[j] = __builtin_amdgcn_mfma_f32_16x16x32_bf16(a1k, b, A1[j], 0, 0, 0);
            }
        }
    };

    // epilogue: exp, row/col accumulate. ALWAYS issues exactly 4 atomic
    // instrs per wave (diag adds 0.f) so vmcnt counts are path-uniform.
    auto epi_half = [&](int c0h, bool bmask, bool isdiag,
                        floatx4 (&A0)[4], floatx4 (&A1)[4]) {
#pragma unroll
        for (int j = 0; j < 4; ++j) {
            const int jj = c0h + j * 16 + m;
            float cs = 0.f;
            if (bmask) {
#pragma unroll
                for (int r = 0; r < 4; ++r) {
                    float e0 = EXP2F(fmaf(A0[j][r], C_EXP, -C_EXP));
                    float e1 = EXP2F(fmaf(A1[j][r], C_EXP, -C_EXP));
                    if (((jj ^ (i0 + r)) & ~B_HALF) == 0) e0 = 0.f;
                    if (((jj ^ (i0 + 16 + r)) & ~B_HALF) == 0) e1 = 0.f;
                    l0[r] += e0;
                    l1[r] += e1;
                    cs += e0 + e1;
                }
            } else {
#pragma unroll
                for (int r = 0; r < 4; ++r) {
                    float e0 = EXP2F(fmaf(A0[j][r], C_EXP, -C_EXP));
                    float e1 = EXP2F(fmaf(A1[j][r], C_EXP, -C_EXP));
                    l0[r] += e0;
                    l1[r] += e1;
                    cs += e0 + e1;
                }
            }
            cs += __shfl_xor(cs, 16, 64);
            cs += __shfl_xor(cs, 32, 64);
            if (isdiag) cs = 0.f;            // diag: col sum would double-count
            if (quad == 0) atomicAdd(&l_arr[jj], cs);
        }
    };

    floatx4 acc0[4], acc1[4];

    // prologue: both buffers' loads in flight (8 per wave)
    stage_half(bj0, 0, buf0);
    stage_half(bj0, 1, buf1);
    __builtin_amdgcn_sched_barrier(0);

    if (has1) {
        // ---- p0: strip0 h0 (buf0) ----  outstanding newer: p1 loads (4)
        asm volatile("s_waitcnt vmcnt(4)" ::: "memory");
        __builtin_amdgcn_s_barrier();
        __builtin_amdgcn_sched_barrier(0);
        mfma_half(buf0, acc0, acc1);
        __builtin_amdgcn_sched_barrier(0);
        __builtin_amdgcn_s_barrier();        // all waves done reading buf0
        stage_half(bj1, 0, buf0);
        __builtin_amdgcn_sched_barrier(0);   // keep atomics AFTER stage loads
        epi_half(bj0 * 128, diag0, diag0, acc0, acc1);
        // ---- p1: strip0 h1 (buf1) ----  newer: p2 loads (4) + epi0 atomics (4)
        asm volatile("s_waitcnt vmcnt(8)" ::: "memory");
        __builtin_amdgcn_s_barrier();
        __builtin_amdgcn_sched_barrier(0);
        mfma_half(buf1, acc0, acc1);
        __builtin_amdgcn_sched_barrier(0);
        __builtin_amdgcn_s_barrier();        // all waves done reading buf1
        stage_half(bj1, 1, buf1);
        __builtin_amdgcn_sched_barrier(0);
        epi_half(bj0 * 128 + 64, diag0, diag0, acc0, acc1);
        // ---- p2: strip1 h0 (buf0) ----  newer: epi0(4) + p3 loads(4) + epi1(4)
        asm volatile("s_waitcnt vmcnt(12)" ::: "memory");
        __builtin_amdgcn_s_barrier();
        __builtin_amdgcn_sched_barrier(0);
        mfma_half(buf0, acc0, acc1);
        __builtin_amdgcn_sched_barrier(0);
        epi_half(bj1 * 128, bmask1, false, acc0, acc1);
        // ---- p3: strip1 h1 (buf1) ----  newer: epi1 atomics(4) + epi2 atomics(4)
        asm volatile("s_waitcnt vmcnt(8)" ::: "memory");
        __builtin_amdgcn_s_barrier();
        __builtin_amdgcn_sched_barrier(0);
        mfma_half(buf1, acc0, acc1);
        __builtin_amdgcn_sched_barrier(0);
        epi_half(bj1 * 128 + 64, bmask1, false, acc0, acc1);
    } else {
        // ---- p0 ----
        asm volatile("s_waitcnt vmcnt(4)" ::: "memory");
        __builtin_amdgcn_s_barrier();
        __builtin_amdgcn_sched_barrier(0);
        mfma_half(buf0, acc0, acc1);
        __builtin_amdgcn_sched_barrier(0);
        epi_half(bj0 * 128, false, false, acc0, acc1);
        // ---- p1 ----  newer: epi0 atomics (4)
        asm volatile("s_waitcnt vmcnt(4)" ::: "memory");
        __builtin_amdgcn_s_barrier();
        __builtin_amdgcn_sched_barrier(0);
        mfma_half(buf1, acc0, acc1);
        __builtin_amdgcn_sched_barrier(0);
        epi_half(bj0 * 128 + 64, false, false, acc0, acc1);
    }

    // ---- per-row reduction + one atomic per row ------------------------
#pragma unroll
    for (int r = 0; r < 4; ++r) {
        float s = l0[r];
        s += __shfl_xor(s, 1, 64);
        s += __shfl_xor(s, 2, 64);
        s += __shfl_xor(s, 4, 64);
        s += __shfl_xor(s, 8, 64);
        if (m == 0) atomicAdd(&l_arr[i0 + r], s);
    }
#pragma unroll
    for (int r = 0; r < 4; ++r) {
        float s = l1[r];
        s += __shfl_xor(s, 1, 64);
        s += __shfl_xor(s, 2, 64);
        s += __shfl_xor(s, 4, 64);
        s += __shfl_xor(s, 8, 64);
        if (m == 0) atomicAdd(&l_arr[i0 + 16 + r], s);
    }

    // ---- folded final reduce: last block computes the loss -------------
    __threadfence();                         // release our atomics
    if (threadIdx.x == 0)
        last_flag = (atomicAdd(cnt, 1u) == (unsigned)NBLK - 1u) ? 1u : 0u;
    __syncthreads();
    if (last_flag) {
        __threadfence();                     // acquire all blocks' atomics
        float s = 0.f;
#pragma unroll
        for (int k2 = 0; k2 < TWO_B / 256; ++k2) {
            int i = threadIdx.x + k2 * 256;
            float lv = __hip_atomic_load(&l_arr[i], __ATOMIC_RELAXED,
                                         __HIP_MEMORY_SCOPE_AGENT);
            s += FIXED_MAX + LOG2F(lv) * 0.6931471805599453f - picked[i];
        }
#pragma unroll
        for (int off = 32; off >= 1; off >>= 1) s += __shfl_xor(s, off, 64);
        if (lane == 0) fred[w] = s;
        __syncthreads();
        if (threadIdx.x == 0)
            out[0] = (fred[0] + fred[1] + fred[2] + fred[3]) * (1.0f / TWO_B);
    }
}

extern "C" void kernel_launch(void* const* d_in, const int* in_sizes, int n_in,
                              void* d_out, int out_size, void* d_ws, size_t ws_size,
                              hipStream_t stream) {
    const float* emb    = (const float*)d_in[0];
    const int*   labels = (const int*)d_in[1];
    char* ws = (char*)d_ws;
    // ws layout: l_arr[8192] f32 | picked[8192] f32 | cnt (4KB pad) | nb bf16
    float*        l_arr  = (float*)ws;
    float*        picked = (float*)(ws + 32768);
    unsigned int* cnt    = (unsigned int*)(ws + 65536);
    __bf16*       nb     = (__bf16*)(ws + 69632);
    float*        out    = (float*)d_out;

    k_prep<<<TWO_B / 4, 256, 0, stream>>>(emb, labels, nb, picked, l_arr, cnt);
    dim3 g2(64, 17);
    k_gemm<<<g2, 256, 0, stream>>>(nb, l_arr, picked, out, cnt);
}

// Round 6
// 157.619 us; speedup vs baseline: 1.2044x; 1.2044x over previous
//
#include <hip/hip_runtime.h>
#include <hip/hip_bf16.h>

// NT-Xent loss, 2B=8192, D=128, T=0.5. TWO dispatches, NO device fences:
//  k_prep : row-normalize -> bf16 nb; picked logit per row (fp32); zero
//           l_arr and the completion counter.
//  k_gemm : SYMMETRIC Gram, upper-triangle 128x128 tiles via circulant
//           pairing bj=(bi+by)&63, by in [0,32]. Block (bi,g) handles TWO
//           strips {g, g+17}; A fragments loaded once; row sums carried in
//           registers across both strips. Single 32 KB LDS buffer staged
//           via global_load_lds (R0's proven structure: plain
//           __syncthreads, straight-line macro code - v5's lambdas spilled
//           accs to scratch, WRITE_SIZE 46 MB, 134 us).
//           v6 deltas vs R0:
//            - column sums: quad-shfl reduce into REGISTER arrays, ALL
//              atomics deferred to kernel end (no barrier/drain ever waits
//              on an atomic; removes the 2-barrier LDS col reduce).
//            - k_final folded in: threadfence + counter, last block
//              reduces 2 + ln(l_arr[i]) - picked[i] into out.
//           Fixed softmax max = 2.0 (cos<=1).
//  (v6 resubmission: previous round died to a container infra failure,
//   not a kernel result - no deadlock possible here: single atomicAdd per
//   block, no spin-wait, cnt re-zeroed by k_prep each launch.)

typedef __bf16 bf16x8 __attribute__((ext_vector_type(8)));
typedef float floatx4 __attribute__((ext_vector_type(4)));

#define TWO_B 8192
#define B_HALF 4096
#define D 128
#define INV_T 2.0f                 // 1/temperature
#define FIXED_MAX 2.0f             // logit upper bound (cos<=1)
#define C_EXP 2.885390081777927f   // INV_T * log2(e) == FIXED_MAX * log2(e)
#define NBLK (64 * 17)

#if defined(__has_builtin) && __has_builtin(__builtin_amdgcn_exp2f)
#define EXP2F(x) __builtin_amdgcn_exp2f(x)   // raw v_exp_f32; arg in [-5.8, 0]
#else
#define EXP2F(x) exp2f(x)
#endif
#if defined(__has_builtin) && __has_builtin(__builtin_amdgcn_logf)
#define LOG2F(x) __builtin_amdgcn_logf(x)    // raw v_log_f32 (log2)
#else
#define LOG2F(x) log2f(x)
#endif

__device__ inline void load16_lds(const __bf16* g, __bf16* l) {
    __builtin_amdgcn_global_load_lds(
        (const __attribute__((address_space(1))) unsigned int*)g,
        (__attribute__((address_space(3))) unsigned int*)l, 16, 0, 0);
}

// -------- kernel 1: normalize + picked + zero l_arr & counter ------------
__global__ void k_prep(const float* __restrict__ emb,
                       const int* __restrict__ labels,
                       __bf16* __restrict__ nb,
                       float* __restrict__ picked,
                       float* __restrict__ l_arr,
                       unsigned int* __restrict__ cnt) {
    int wv   = threadIdx.x >> 6;
    int lane = threadIdx.x & 63;
    int i = blockIdx.x * 4 + wv;
    const float2* e2 = reinterpret_cast<const float2*>(emb + (size_t)i * D);
    float2 v = e2[lane];
    float ssi = v.x * v.x + v.y * v.y;
    // picked column: labels[i] skips cols {i, i^4096}
    int p = i ^ B_HALF;
    int a = min(i, p), b = max(i, p);
    int l = labels[i];
    int c = l + (l >= a);
    c += (c >= b);
    const float2* ec2 = reinterpret_cast<const float2*>(emb + (size_t)c * D);
    float2 u = ec2[lane];
    float dot = v.x * u.x + v.y * u.y;
    float ssc = u.x * u.x + u.y * u.y;
#pragma unroll
    for (int off = 32; off >= 1; off >>= 1) {
        ssi += __shfl_xor(ssi, off, 64);
        dot += __shfl_xor(dot, off, 64);
        ssc += __shfl_xor(ssc, off, 64);
    }
    float rn = rsqrtf(fmaxf(ssi, 1e-16f));
    union { __bf16 h[2]; unsigned int uu; } pk;
    pk.h[0] = (__bf16)(v.x * rn);
    pk.h[1] = (__bf16)(v.y * rn);
    reinterpret_cast<unsigned int*>(nb)[i * 64 + lane] = pk.uu;
    if (lane == 0)
        picked[i] = dot / fmaxf(sqrtf(ssi * ssc), 1e-8f) * INV_T;
    if (blockIdx.x < TWO_B / 256) l_arr[blockIdx.x * 256 + threadIdx.x] = 0.f;
    if (blockIdx.x == 0 && threadIdx.x == 0) *cnt = 0u;
}

// One full 128x128 strip: 2 groups x 4 sub-tiles, 8 independent MFMA
// chains; epilogue computes exp, row sums (l0/l1) and per-sub column sums
// quad-reduced into CS[0..7] (register array, static indices). No atomics
// here - they are all deferred to kernel end.
#define COMPUTE_STRIP(C0, BMASK, CS)                                          \
    do {                                                                      \
        _Pragma("unroll")                                                     \
        for (int grp = 0; grp < 2; ++grp) {                                   \
            floatx4 acc0[4] = {{0.f,0.f,0.f,0.f},{0.f,0.f,0.f,0.f},           \
                               {0.f,0.f,0.f,0.f},{0.f,0.f,0.f,0.f}};          \
            floatx4 acc1[4] = {{0.f,0.f,0.f,0.f},{0.f,0.f,0.f,0.f},           \
                               {0.f,0.f,0.f,0.f},{0.f,0.f,0.f,0.f}};          \
            _Pragma("unroll")                                                 \
            for (int kc = 0; kc < 4; ++kc) {                                  \
                const bf16x8 a0k = a0[kc], a1k = a1[kc];                      \
                _Pragma("unroll")                                             \
                for (int s = 0; s < 4; ++s) {                                 \
                    bf16x8 b = *reinterpret_cast<const bf16x8*>(              \
                        &lds[((grp * 4 + s) * 4 + kc) * 512 + lane * 8]);     \
                    acc0[s] = __builtin_amdgcn_mfma_f32_16x16x32_bf16(a0k, b, acc0[s], 0, 0, 0); \
                    acc1[s] = __builtin_amdgcn_mfma_f32_16x16x32_bf16(a1k, b, acc1[s], 0, 0, 0); \
                }                                                             \
            }                                                                 \
            _Pragma("unroll")                                                 \
            for (int s = 0; s < 4; ++s) {                                     \
                const int jj = (C0) + (grp * 4 + s) * 16 + m;                 \
                float cs = 0.f;                                               \
                if (BMASK) {                                                  \
                    _Pragma("unroll")                                         \
                    for (int r = 0; r < 4; ++r) {                             \
                        float e0 = EXP2F(fmaf(acc0[s][r], C_EXP, -C_EXP));    \
                        float e1 = EXP2F(fmaf(acc1[s][r], C_EXP, -C_EXP));    \
                        if (((jj ^ (i0 + r)) & ~B_HALF) == 0) e0 = 0.f;       \
                        if (((jj ^ (i0 + 16 + r)) & ~B_HALF) == 0) e1 = 0.f;  \
                        l0[r] += e0;                                          \
                        l1[r] += e1;                                          \
                        cs += e0 + e1;                                        \
                    }                                                         \
                } else {                                                      \
                    _Pragma("unroll")                                         \
                    for (int r = 0; r < 4; ++r) {                             \
                        float e0 = EXP2F(fmaf(acc0[s][r], C_EXP, -C_EXP));    \
                        float e1 = EXP2F(fmaf(acc1[s][r], C_EXP, -C_EXP));    \
                        l0[r] += e0;                                          \
                        l1[r] += e1;                                          \
                        cs += e0 + e1;                                        \
                    }                                                         \
                }                                                             \
                cs += __shfl_xor(cs, 16, 64);                                 \
                cs += __shfl_xor(cs, 32, 64);                                 \
                CS[grp * 4 + s] = cs;                                         \
            }                                                                 \
        }                                                                     \
    } while (0)

// -------- kernel 2: symmetric Gram MFMA + masked exp-sum + final ---------
// grid (64, 17), block 256 = 4 waves.
__global__ __launch_bounds__(256, 4) void k_gemm(const __bf16* __restrict__ nb,
                                                 float* __restrict__ l_arr,
                                                 const float* __restrict__ picked,
                                                 float* __restrict__ out,
                                                 unsigned int* __restrict__ cnt) {
    __shared__ __bf16 lds[16384];            // 32 KB: 128 cols x K=128
    __shared__ unsigned int last_flag;
    __shared__ float fred[4];

    const int bi = blockIdx.x;
    const int g  = blockIdx.y;

    const int lane = threadIdx.x & 63;
    const int w    = threadIdx.x >> 6;
    const int m    = lane & 15;
    const int quad = lane >> 4;
    const int row0 = bi * 128 + w * 32;      // wave rows: row0..row0+31

    // A fragments: two 16-row tiles, full K=128, pinned, loaded ONCE
    bf16x8 a0[4], a1[4];
#pragma unroll
    for (int kc = 0; kc < 4; ++kc) {
        a0[kc] = *reinterpret_cast<const bf16x8*>(
            nb + (size_t)(row0 + m) * D + kc * 32 + quad * 8);
        a1[kc] = *reinterpret_cast<const bf16x8*>(
            nb + (size_t)(row0 + 16 + m) * D + kc * 32 + quad * 8);
    }
    asm volatile("" : "+v"(a0[0]), "+v"(a0[1]), "+v"(a0[2]), "+v"(a0[3]),
                      "+v"(a1[0]), "+v"(a1[1]), "+v"(a1[2]), "+v"(a1[3]));

    float l0[4] = {0.f, 0.f, 0.f, 0.f};      // row sums, carried across strips
    float l1[4] = {0.f, 0.f, 0.f, 0.f};
    const int i0 = row0 + quad * 4;          // l0 rows; l1 rows = i0+16

    const int  bj0    = (bi + g) & 63;
    const bool diag0  = (g == 0);
    const bool has1   = (g < 15) || (g == 15 && bi < 32);
    const int  bj1    = (bi + g + 17) & 63;
    const bool bmask1 = (g == 15);           // by==32 partner-pair masking

    float cs0[8], cs1[8];
#pragma unroll
    for (int s = 0; s < 8; ++s) { cs0[s] = 0.f; cs1[s] = 0.f; }

    // ---- strip 0 ---------------------------------------------------------
    // LDS elem j*2048 + w*512 + lane*8+e <-> nb[(C0+16j+m)*D + w*32+quad*8+e]
    {
        const __bf16* gp = nb + (size_t)(bj0 * 128 + m) * D + w * 32 + quad * 8;
#pragma unroll
        for (int j = 0; j < 8; ++j)
            load16_lds(gp + (size_t)j * 16 * D, &lds[j * 2048 + w * 512]);
    }
    __syncthreads();                         // drains vmcnt(0): stage complete
    COMPUTE_STRIP(bj0 * 128, diag0, cs0);

    // ---- strip 1 ---------------------------------------------------------
    if (has1) {
        __syncthreads();                     // all waves done reading strip0 LDS
        const __bf16* gp = nb + (size_t)(bj1 * 128 + m) * D + w * 32 + quad * 8;
#pragma unroll
        for (int j = 0; j < 8; ++j)
            load16_lds(gp + (size_t)j * 16 * D, &lds[j * 2048 + w * 512]);
        __syncthreads();
        COMPUTE_STRIP(bj1 * 128, bmask1, cs1);
    }

    // ---- ALL atomics issued here, after the last barrier -----------------
    // rows: butterfly over m, one atomic per row
#pragma unroll
    for (int r = 0; r < 4; ++r) {
        float s = l0[r];
        s += __shfl_xor(s, 1, 64);
        s += __shfl_xor(s, 2, 64);
        s += __shfl_xor(s, 4, 64);
        s += __shfl_xor(s, 8, 64);
        if (m == 0) atomicAdd(&l_arr[i0 + r], s);
    }
#pragma unroll
    for (int r = 0; r < 4; ++r) {
        float s = l1[r];
        s += __shfl_xor(s, 1, 64);
        s += __shfl_xor(s, 2, 64);
        s += __shfl_xor(s, 4, 64);
        s += __shfl_xor(s, 8, 64);
        if (m == 0) atomicAdd(&l_arr[i0 + 16 + r], s);
    }
    // cols: quad==0 lanes hold the 32-row-reduced sums (diag tile skipped:
    // its column contributions equal its row contributions, already counted)
    if (!diag0 && quad == 0) {
#pragma unroll
        for (int s = 0; s < 8; ++s)
            atomicAdd(&l_arr[bj0 * 128 + s * 16 + m], cs0[s]);
    }
    if (has1 && quad == 0) {
#pragma unroll
        for (int s = 0; s < 8; ++s)
            atomicAdd(&l_arr[bj1 * 128 + s * 16 + m], cs1[s]);
    }

    // ---- folded final reduce: last block computes the loss ---------------
    __threadfence();                         // release our atomics
    if (threadIdx.x == 0)
        last_flag = (atomicAdd(cnt, 1u) == (unsigned)NBLK - 1u) ? 1u : 0u;
    __syncthreads();
    if (last_flag) {
        __threadfence();                     // acquire all blocks' atomics
        float s = 0.f;
#pragma unroll
        for (int k2 = 0; k2 < TWO_B / 256; ++k2) {
            int i = threadIdx.x + k2 * 256;
            float lv = __hip_atomic_load(&l_arr[i], __ATOMIC_RELAXED,
                                         __HIP_MEMORY_SCOPE_AGENT);
            s += FIXED_MAX + LOG2F(lv) * 0.6931471805599453f - picked[i];
        }
#pragma unroll
        for (int off = 32; off >= 1; off >>= 1) s += __shfl_xor(s, off, 64);
        if (lane == 0) fred[w] = s;
        __syncthreads();
        if (threadIdx.x == 0)
            out[0] = (fred[0] + fred[1] + fred[2] + fred[3]) * (1.0f / TWO_B);
    }
}

extern "C" void kernel_launch(void* const* d_in, const int* in_sizes, int n_in,
                              void* d_out, int out_size, void* d_ws, size_t ws_size,
                              hipStream_t stream) {
    const float* emb    = (const float*)d_in[0];
    const int*   labels = (const int*)d_in[1];
    char* ws = (char*)d_ws;
    // ws layout: l_arr[8192] f32 | picked[8192] f32 | cnt (4KB pad) | nb bf16
    float*        l_arr  = (float*)ws;
    float*        picked = (float*)(ws + 32768);
    unsigned int* cnt    = (unsigned int*)(ws + 65536);
    __bf16*       nb     = (__bf16*)(ws + 69632);
    float*        out    = (float*)d_out;

    k_prep<<<TWO_B / 4, 256, 0, stream>>>(emb, labels, nb, picked, l_arr, cnt);
    dim3 g2(64, 17);
    k_gemm<<<g2, 256, 0, stream>>>(nb, l_arr, picked, out, cnt);
}

// Round 7
// 84.891 us; speedup vs baseline: 2.2361x; 1.8567x over previous
//
#include <hip/hip_runtime.h>
#include <hip/hip_bf16.h>

// NT-Xent loss, 2B=8192, D=128, T=0.5. THREE dispatches, NO device fences:
//  k_prep : row-normalize -> bf16 nb; picked logit per row (fp32); zero l_arr.
//  k_gemm : SYMMETRIC Gram, upper-triangle 128x128 tiles via circulant
//           pairing bj=(bi+by)&63, by in [0,32]. Each block handles TWO
//           strips {g, g+17} for one row-block: A fragments loaded once,
//           row sums accumulated in registers across both tiles (atomics
//           once). Single 32 KB LDS buffer staged via global_load_lds,
//           plain __syncthreads (R0's proven structure - every attempt to
//           restructure staging/registers lost to the compiler's 64-VGPR
//           ceiling: v2/v3 global-direct 46-48us, v5/v6 deferred-reg
//           col-sums spilled to scratch, 103-134us).
//           v7 sole delta vs R0: column sums via quad-shfl reduce +
//           IMMEDIATE atomicAdd (v2-verified, zero carried registers)
//           instead of the 2-barrier LDS cross-wave reduce. Barriers per
//           block: 7 -> 3. Fixed softmax max = 2.0 (cos<=1).
//  k_final: 1 block (1024 thr) reduces 2 + ln(l_arr[i]) - picked[i].

typedef __bf16 bf16x8 __attribute__((ext_vector_type(8)));
typedef float floatx4 __attribute__((ext_vector_type(4)));

#define TWO_B 8192
#define B_HALF 4096
#define D 128
#define INV_T 2.0f                 // 1/temperature
#define FIXED_MAX 2.0f             // logit upper bound (cos<=1)
#define C_EXP 2.885390081777927f   // INV_T * log2(e) == FIXED_MAX * log2(e)

#if defined(__has_builtin) && __has_builtin(__builtin_amdgcn_exp2f)
#define EXP2F(x) __builtin_amdgcn_exp2f(x)   // raw v_exp_f32; arg in [-5.8, 0]
#else
#define EXP2F(x) exp2f(x)
#endif
#if defined(__has_builtin) && __has_builtin(__builtin_amdgcn_logf)
#define LOG2F(x) __builtin_amdgcn_logf(x)    // raw v_log_f32 (log2)
#else
#define LOG2F(x) log2f(x)
#endif

__device__ inline void load16_lds(const __bf16* g, __bf16* l) {
    __builtin_amdgcn_global_load_lds(
        (const __attribute__((address_space(1))) unsigned int*)g,
        (__attribute__((address_space(3))) unsigned int*)l, 16, 0, 0);
}

// -------- kernel 1: normalize + picked + zero l_arr ----------------------
__global__ void k_prep(const float* __restrict__ emb,
                       const int* __restrict__ labels,
                       __bf16* __restrict__ nb,
                       float* __restrict__ picked,
                       float* __restrict__ l_arr) {
    int wv   = threadIdx.x >> 6;
    int lane = threadIdx.x & 63;
    int i = blockIdx.x * 4 + wv;
    const float2* e2 = reinterpret_cast<const float2*>(emb + (size_t)i * D);
    float2 v = e2[lane];
    float ssi = v.x * v.x + v.y * v.y;
    // picked column: labels[i] skips cols {i, i^4096}
    int p = i ^ B_HALF;
    int a = min(i, p), b = max(i, p);
    int l = labels[i];
    int c = l + (l >= a);
    c += (c >= b);
    const float2* ec2 = reinterpret_cast<const float2*>(emb + (size_t)c * D);
    float2 u = ec2[lane];
    float dot = v.x * u.x + v.y * u.y;
    float ssc = u.x * u.x + u.y * u.y;
#pragma unroll
    for (int off = 32; off >= 1; off >>= 1) {
        ssi += __shfl_xor(ssi, off, 64);
        dot += __shfl_xor(dot, off, 64);
        ssc += __shfl_xor(ssc, off, 64);
    }
    float rn = rsqrtf(fmaxf(ssi, 1e-16f));
    union { __bf16 h[2]; unsigned int uu; } pk;
    pk.h[0] = (__bf16)(v.x * rn);
    pk.h[1] = (__bf16)(v.y * rn);
    reinterpret_cast<unsigned int*>(nb)[i * 64 + lane] = pk.uu;
    if (lane == 0)
        picked[i] = dot / fmaxf(sqrtf(ssi * ssc), 1e-8f) * INV_T;
    if (blockIdx.x < TWO_B / 256) l_arr[blockIdx.x * 256 + threadIdx.x] = 0.f;
}

// -------- kernel 2: symmetric Gram MFMA + masked exp-sum -----------------
// grid (64, 17), block 256 = 4 waves. Block (bi,g): rows bi*128, strips
// by in {g, g+17} (by<=32; by==32 only valid for bi<32; by==0 = diagonal).
__global__ __launch_bounds__(256, 4) void k_gemm(const __bf16* __restrict__ nb,
                                                 float* __restrict__ l_arr) {
    __shared__ __bf16 lds[16384];            // 32 KB: 128 cols x K=128

    const int bi = blockIdx.x;
    const int g  = blockIdx.y;

    const int lane = threadIdx.x & 63;
    const int w    = threadIdx.x >> 6;
    const int m    = lane & 15;
    const int quad = lane >> 4;
    const int row0 = bi * 128 + w * 32;      // wave rows: row0..row0+31

    // A fragments: two 16-row tiles, full K=128, pinned, loaded ONCE
    bf16x8 a0[4], a1[4];
#pragma unroll
    for (int kc = 0; kc < 4; ++kc) {
        a0[kc] = *reinterpret_cast<const bf16x8*>(
            nb + (size_t)(row0 + m) * D + kc * 32 + quad * 8);
        a1[kc] = *reinterpret_cast<const bf16x8*>(
            nb + (size_t)(row0 + 16 + m) * D + kc * 32 + quad * 8);
    }
    asm volatile("" : "+v"(a0[0]), "+v"(a0[1]), "+v"(a0[2]), "+v"(a0[3]),
                      "+v"(a1[0]), "+v"(a1[1]), "+v"(a1[2]), "+v"(a1[3]));

    float l0[4] = {0.f, 0.f, 0.f, 0.f};      // row sums, carried across strips
    float l1[4] = {0.f, 0.f, 0.f, 0.f};
    const int i0 = row0 + quad * 4;          // l0 rows; l1 rows = i0+16

    bool first = true;
#pragma unroll
    for (int si = 0; si < 2; ++si) {
        const int by = g + si * 17;
        if (by > 32) continue;               // g==16 has a single strip
        if (by == 32 && bi >= 32) continue;  // circulant duplicate
        const int bj = (bi + by) & 63;
        const int C0 = bj * 128;
        const bool isdiag = (by == 0);
        const bool bmask = isdiag || (by == 32);

        if (!first) __syncthreads();         // prior LDS readers done
        first = false;

        // ---- stage 128 cols x 128 K into LDS, fragment order ------------
        {
            const __bf16* gp = nb + (size_t)(C0 + m) * D + w * 32 + quad * 8;
#pragma unroll
            for (int j = 0; j < 8; ++j)
                load16_lds(gp + (size_t)j * 16 * D, &lds[j * 2048 + w * 512]);
        }
        __syncthreads();   // compiler drains vmcnt(0) before barrier

        // ---- two groups of 4 sub-tiles; 8 independent MFMA chains -------
#pragma unroll
        for (int grp = 0; grp < 2; ++grp) {
            floatx4 acc0[4] = {{0.f,0.f,0.f,0.f},{0.f,0.f,0.f,0.f},
                               {0.f,0.f,0.f,0.f},{0.f,0.f,0.f,0.f}};
            floatx4 acc1[4] = {{0.f,0.f,0.f,0.f},{0.f,0.f,0.f,0.f},
                               {0.f,0.f,0.f,0.f},{0.f,0.f,0.f,0.f}};
#pragma unroll
            for (int kc = 0; kc < 4; ++kc) {
                const bf16x8 a0k = a0[kc], a1k = a1[kc];
#pragma unroll
                for (int s = 0; s < 4; ++s) {
                    bf16x8 b = *reinterpret_cast<const bf16x8*>(
                        &lds[((grp * 4 + s) * 4 + kc) * 512 + lane * 8]);
                    acc0[s] = __builtin_amdgcn_mfma_f32_16x16x32_bf16(a0k, b, acc0[s], 0, 0, 0);
                    acc1[s] = __builtin_amdgcn_mfma_f32_16x16x32_bf16(a1k, b, acc1[s], 0, 0, 0);
                }
            }
            // ---- epilogue: exp, row-accumulate, col quad-reduce+atomic --
#pragma unroll
            for (int s = 0; s < 4; ++s) {
                const int jj = C0 + (grp * 4 + s) * 16 + m;
                float cs = 0.f;
                if (bmask) {
#pragma unroll
                    for (int r = 0; r < 4; ++r) {
                        float e0 = EXP2F(fmaf(acc0[s][r], C_EXP, -C_EXP));
                        float e1 = EXP2F(fmaf(acc1[s][r], C_EXP, -C_EXP));
                        if (((jj ^ (i0 + r)) & ~B_HALF) == 0) e0 = 0.f;
                        if (((jj ^ (i0 + 16 + r)) & ~B_HALF) == 0) e1 = 0.f;
                        l0[r] += e0;
                        l1[r] += e1;
                        cs += e0 + e1;
                    }
                } else {
#pragma unroll
                    for (int r = 0; r < 4; ++r) {
                        float e0 = EXP2F(fmaf(acc0[s][r], C_EXP, -C_EXP));
                        float e1 = EXP2F(fmaf(acc1[s][r], C_EXP, -C_EXP));
                        l0[r] += e0;
                        l1[r] += e1;
                        cs += e0 + e1;
                    }
                }
                // full 32-row column sum for col jj (sum across quads),
                // consumed immediately: zero carried registers (v2-verified)
                if (!isdiag) {
                    cs += __shfl_xor(cs, 16, 64);
                    cs += __shfl_xor(cs, 32, 64);
                    if (quad == 0) atomicAdd(&l_arr[jj], cs);
                }
            }
        }
    }

    // ---- per-row reduction + one atomic per row (once per block) --------
#pragma unroll
    for (int r = 0; r < 4; ++r) {
        float s = l0[r];
        s += __shfl_xor(s, 1, 64);
        s += __shfl_xor(s, 2, 64);
        s += __shfl_xor(s, 4, 64);
        s += __shfl_xor(s, 8, 64);
        if (m == 0) atomicAdd(&l_arr[i0 + r], s);
    }
#pragma unroll
    for (int r = 0; r < 4; ++r) {
        float s = l1[r];
        s += __shfl_xor(s, 1, 64);
        s += __shfl_xor(s, 2, 64);
        s += __shfl_xor(s, 4, 64);
        s += __shfl_xor(s, 8, 64);
        if (m == 0) atomicAdd(&l_arr[i0 + 16 + r], s);
    }
}

// -------- kernel 3: single-block final reduce (1024 threads) -------------
__global__ void k_final(const float* __restrict__ l_arr,
                        const float* __restrict__ picked,
                        float* __restrict__ out) {
    __shared__ float sred[16];
    float s = 0.f;
#pragma unroll
    for (int k = 0; k < TWO_B / 1024; ++k) {
        int i = threadIdx.x + k * 1024;
        s += FIXED_MAX + LOG2F(l_arr[i]) * 0.6931471805599453f - picked[i];
    }
#pragma unroll
    for (int off = 32; off >= 1; off >>= 1) s += __shfl_xor(s, off, 64);
    if ((threadIdx.x & 63) == 0) sred[threadIdx.x >> 6] = s;
    __syncthreads();
    if (threadIdx.x == 0) {
        float t = 0.f;
#pragma unroll
        for (int k = 0; k < 16; ++k) t += sred[k];
        out[0] = t * (1.0f / TWO_B);
    }
}

extern "C" void kernel_launch(void* const* d_in, const int* in_sizes, int n_in,
                              void* d_out, int out_size, void* d_ws, size_t ws_size,
                              hipStream_t stream) {
    const float* emb    = (const float*)d_in[0];
    const int*   labels = (const int*)d_in[1];
    char* ws = (char*)d_ws;
    // ws layout: l_arr[8192] f32 | picked[8192] f32 | nb bf16[8192*128]
    float*  l_arr  = (float*)ws;
    float*  picked = (float*)(ws + 32768);
    __bf16* nb     = (__bf16*)(ws + 65536);
    float*  out    = (float*)d_out;

    k_prep<<<TWO_B / 4, 256, 0, stream>>>(emb, labels, nb, picked, l_arr);
    dim3 g2(64, 17);
    k_gemm<<<g2, 256, 0, stream>>>(nb, l_arr);
    k_final<<<1, 1024, 0, stream>>>(l_arr, picked, out);
}